// Round 10
// baseline (392.079 us; speedup 1.0000x reference)
//
#include <hip/hip_runtime.h>
#include <hip/hip_bf16.h>
#include <hip/hip_fp16.h>
#include <math.h>

// Problem dims
#define B 64
#define S 2048
#define E 512
#define HD 512
#define TD 128
#define M_TOT (B*S)
#define MTILE 64
#define NCHUNK (M_TOT/MTILE)    // 2048 k3 chunks (32 per batch)

// Workspace layout (in floats)
#define OFF_MASK   0                        // B*S
#define OFF_CTXP   (OFF_MASK + B*S)         // 8*B*E
#define OFF_LENP   (OFF_CTXP + 8*B*E)       // 8*B
#define OFF_CB     (OFF_LENP + 8*B)         // B*HD
#define OFF_PP     (OFF_CB + B*HD)          // NCHUNK*E   P partials
#define OFF_ML     (OFF_PP + NCHUNK*E)      // NCHUNK     local maxima
#define OFF_LL     (OFF_ML + NCHUNK)        // NCHUNK     local exp-sums
#define OFF_WPK    (OFF_LL + NCHUNK)        // 262144 fp16 = 131072 floats

typedef __attribute__((ext_vector_type(8))) short short8;
typedef __attribute__((ext_vector_type(4))) float f32x4;

__device__ inline unsigned int f2hu(float x) {
    __half h = __float2half(x);
    unsigned short u; __builtin_memcpy(&u, &h, 2); return (unsigned int)u;
}

// fast tanh: exact saturation, ~1e-6 rel err, no NaN (e in (0,1])
__device__ inline float fast_tanh(float x) {
    float a = fabsf(x);
    float e = __expf(-2.0f * a);
    float r = (1.0f - e) / (1.0f + e);
    return copysignf(r, x);
}

#define GLOAD_LDS16(gpu, lds) \
    __builtin_amdgcn_global_load_lds((__attribute__((address_space(1))) const void*)(gpu), \
                                     (__attribute__((address_space(3))) void*)(lds), 16, 0, 0)

// pack 8 fp32 (lo,hi) -> 8 fp16 (RNE)
__device__ inline short8 pack8h(const f32x4 lo, const f32x4 hi) {
    union { short8 s; __half2 h[4]; } u;
    u.h[0] = __float22half2_rn(make_float2(lo[0], lo[1]));
    u.h[1] = __float22half2_rn(make_float2(lo[2], lo[3]));
    u.h[2] = __float22half2_rn(make_float2(hi[0], hi[1]));
    u.h[3] = __float22half2_rn(make_float2(hi[2], hi[3]));
    return u.s;
}

// ---------------------------------------------------------------------------
// k0: pack top half of W_att into MFMA B-fragment layout, fp16.
// 16x16x32 f16 B-frag: lane l holds B[k=(l>>4)*8+j][col=l&15].
// Wpk[kstep][fl(32)][lane(64)][j(8)], fl = h>>4
// ---------------------------------------------------------------------------
__global__ __launch_bounds__(256)
void k0_pack(const float* __restrict__ W_att, unsigned short* __restrict__ Wpk)
{
    int tid = blockIdx.x*256 + threadIdx.x;   // 262144 total
    int e = tid >> 9, h = tid & 511;
    float w = W_att[(size_t)e*HD + h];
    int kstep = e >> 5, kb = (e >> 3) & 3, j = e & 7, f = h >> 4, l15 = h & 15;
    size_t dst = ((((size_t)kstep*32 + f)*64) + kb*16 + l15)*8 + j;
    Wpk[dst] = (unsigned short)f2hu(w);
}

// ---------------------------------------------------------------------------
// K1: mask, column partial sums, lengths
// ---------------------------------------------------------------------------
__global__ __launch_bounds__(256)
void k1_maskcol(const float* __restrict__ words, float* __restrict__ mask,
                float* __restrict__ ctxp, float* __restrict__ lenp)
{
    int bid = blockIdx.x;            // 512 = B * 8
    int b = bid >> 3, ch = bid & 7;
    int t = threadIdx.x;
    int w = t >> 6, l = t & 63;
    __shared__ __align__(16) float colred[4][E];
    __shared__ float lenred[4];
    const float* base = words + (size_t)(b * S + ch * 256) * E;
    float4 c0 = make_float4(0.f,0.f,0.f,0.f), c1 = make_float4(0.f,0.f,0.f,0.f);
    float wlen = 0.0f;
    for (int r = w; r < 256; r += 4) {
        const float* row = base + (size_t)r * E;
        float4 a  = *(const float4*)(row + 4*l);
        float4 bb = *(const float4*)(row + 256 + 4*l);
        float rs = a.x+a.y+a.z+a.w + bb.x+bb.y+bb.z+bb.w;
        #pragma unroll
        for (int m = 1; m < 64; m <<= 1) rs += __shfl_xor(rs, m);
        c0.x += a.x;  c0.y += a.y;  c0.z += a.z;  c0.w += a.w;
        c1.x += bb.x; c1.y += bb.y; c1.z += bb.z; c1.w += bb.w;
        if (l == 0) {
            float mv = (rs != 0.0f) ? 1.0f : 0.0f;
            mask[(size_t)b*S + ch*256 + r] = mv;
            wlen += mv;
        }
    }
    *(float4*)&colred[w][4*l]       = c0;
    *(float4*)&colred[w][256 + 4*l] = c1;
    if (l == 0) lenred[w] = wlen;
    __syncthreads();
    float s1 = colred[0][t]+colred[1][t]+colred[2][t]+colred[3][t];
    float s2 = colred[0][t+256]+colred[1][t+256]+colred[2][t+256]+colred[3][t+256];
    size_t o = ((size_t)ch * B + b) * E;
    ctxp[o + t]       = s1;
    ctxp[o + t + 256] = s2;
    if (t == 0) lenp[ch*B + b] = lenred[0]+lenred[1]+lenred[2]+lenred[3];
}

// ---------------------------------------------------------------------------
// K2: cb[b,h] = b_att[h] + context_b . W_att[E:, h]
// ---------------------------------------------------------------------------
__global__ __launch_bounds__(256)
void k2_cb(const float* __restrict__ W_att, const float* __restrict__ b_att,
           const float* __restrict__ ctxp, const float* __restrict__ lenp,
           float* __restrict__ cb)
{
    int bid = blockIdx.x;            // 128
    int b = bid >> 1, hc = bid & 1;
    int t = threadIdx.x;
    __shared__ float ctxL[E];
    float len = 0.f;
    #pragma unroll
    for (int k = 0; k < 8; ++k) len += lenp[k*B + b];
    float inv = 1.0f / len;
    for (int c = t; c < E; c += 256) {
        float sv = 0.f;
        #pragma unroll
        for (int k = 0; k < 8; ++k) sv += ctxp[((size_t)k*B + b)*E + c];
        ctxL[c] = sv * inv;
    }
    __syncthreads();
    int h = hc*256 + t;
    const float* Wb = W_att + (size_t)E * HD;
    float a0 = b_att[h], a1 = 0.f, a2 = 0.f, a3 = 0.f;
    #pragma unroll 4
    for (int e = 0; e < E; e += 4) {
        a0 += ctxL[e]   * Wb[(size_t)e*HD + h];
        a1 += ctxL[e+1] * Wb[(size_t)(e+1)*HD + h];
        a2 += ctxL[e+2] * Wb[(size_t)(e+2)*HD + h];
        a3 += ctxL[e+3] * Wb[(size_t)(e+3)*HD + h];
    }
    cb[(size_t)b*HD + h] = (a0 + a1) + (a2 + a3);
}

// ---------------------------------------------------------------------------
// K3: fp16 MFMA scores + fused local softmax + P-partials.
// Block tile 64(M) x 512(N), 8 waves (2wr x 4wc), wave 32x128, acc[2][8].
// A: whole fp32 tile DMA'd to LDS ONCE via global_load_lds with a
//    source-permuted XOR swizzle (granule n=row*128+(g^(row&7)), written
//    linearly) -> zero staging, zero main-loop barriers, even bank spread.
// B: kstep-level register double-buffer from packed Wpk (L2-resident).
// Epilogue P reads the fp32 LDS tile (no HBM re-read).
// ---------------------------------------------------------------------------
__global__ __launch_bounds__(512, 2)
void k3_scores(const float* __restrict__ words,
               const unsigned short* __restrict__ Wpk,
               const float* __restrict__ cb, const float* __restrict__ v,
               const float* __restrict__ mask,
               float* __restrict__ Pp, float* __restrict__ Ml, float* __restrict__ Ll)
{
    // 128 KB fp32 A-tile + 2.6 KB epilogue scratch
    __shared__ __align__(16) unsigned char smem[131072 + 2608];
    int mt = blockIdx.x;              // 2048 mtiles of 64 rows
    int m0 = mt * MTILE;
    int b  = m0 >> 11;                // S = 2048
    int t = threadIdx.x;
    int lane = t & 63, wid = t >> 6;
    int wr = wid >> 2, wc = wid & 3;  // 2 row-groups x 4 col-groups

    f32x4 acc[2][8];
    #pragma unroll
    for (int i = 0; i < 2; ++i)
        #pragma unroll
        for (int j = 0; j < 8; ++j) acc[i][j] = (f32x4)0.0f;

    // ---- prologue: DMA the whole 64x512 fp32 tile to LDS, source-permuted.
    // LDS granule n = i*64 + lane  (i = DMA instr index 0..127, 1KB each)
    //   row = i>>1, gs = (i&1)*64 + lane, g = gs ^ (row&7)
    // so LDS[row][gs] holds global granule (row, g): read side XORs the same.
    {
        #pragma unroll
        for (int ii = 0; ii < 16; ++ii) {
            int i = wid*16 + ii;
            int row = i >> 1;
            int g = (((i & 1) << 6) | lane) ^ (row & 7);
            const float* src = words + (size_t)(m0 + row)*E + g*4;
            GLOAD_LDS16(src, &smem[i*1024]);
        }
    }

    // ---- B fragment base: frag fl = wc*8 + cf  (all 512 cols in-block)
    const unsigned short* bBase = Wpk + (((size_t)(wc*8))*64 + lane)*8;
#define LDB(kst,cf) (*(const short8*)(bBase + ((size_t)(kst)*32 + (cf))*512))

    short8 bA[8], bB[8];
    #pragma unroll
    for (int cf = 0; cf < 8; ++cf) bA[cf] = LDB(0, cf);
    __syncthreads();   // DMA + B(0) complete; tile is read-only from here

    // ---- barrier-free main loop: 16 ksteps, fully unrolled
    int arow0 = wr*32 + (lane & 15);          // rf=0 row
    int klane = ((lane >> 4) & 3) * 2;        // granule pair base within kstep
#define KBODY(k, BCUR, BNEXT) do { \
        short8 ah[2]; \
        _Pragma("unroll") \
        for (int rf = 0; rf < 2; ++rf) { \
            int row = arow0 + rf*16; \
            int g0 = (k)*8 + klane; \
            int swz = row & 7; \
            f32x4 lo = *(const f32x4*)&smem[row*2048 + ((g0    ) ^ swz)*16]; \
            f32x4 hi = *(const f32x4*)&smem[row*2048 + ((g0 + 1) ^ swz)*16]; \
            ah[rf] = pack8h(lo, hi); \
        } \
        if ((k) < 15) { \
            _Pragma("unroll") \
            for (int cf = 0; cf < 8; ++cf) BNEXT[cf] = LDB((k)+1, cf); \
        } \
        _Pragma("unroll") \
        for (int cf = 0; cf < 8; ++cf) { \
            _Pragma("unroll") \
            for (int rf = 0; rf < 2; ++rf) \
                acc[rf][cf] = __builtin_amdgcn_mfma_f32_16x16x32_f16(ah[rf], BCUR[cf], acc[rf][cf], 0, 0, 0); \
        } } while(0)

    KBODY( 0, bA, bB);  KBODY( 1, bB, bA);
    KBODY( 2, bA, bB);  KBODY( 3, bB, bA);
    KBODY( 4, bA, bB);  KBODY( 5, bB, bA);
    KBODY( 6, bA, bB);  KBODY( 7, bB, bA);
    KBODY( 8, bA, bB);  KBODY( 9, bB, bA);
    KBODY(10, bA, bB);  KBODY(11, bB, bA);
    KBODY(12, bA, bB);  KBODY(13, bB, bA);
    KBODY(14, bA, bB);  KBODY(15, bB, bA);
#undef KBODY
#undef LDB

    // ---- epilogue 1: tanh(+cb)*v, reduce to per-row raw scores
    float ssum[2][4];
    #pragma unroll
    for (int i = 0; i < 2; ++i)
        #pragma unroll
        for (int rr = 0; rr < 4; ++rr) ssum[i][rr] = 0.f;

    #pragma unroll
    for (int cf = 0; cf < 8; ++cf) {
        int col = wc*128 + cf*16 + (lane & 15);
        float cbv = cb[(size_t)b*HD + col];
        float vv  = v[col];
        #pragma unroll
        for (int rf = 0; rf < 2; ++rf)
            #pragma unroll
            for (int rr = 0; rr < 4; ++rr)
                ssum[rf][rr] += fast_tanh(acc[rf][cf][rr] + cbv) * vv;
    }
    #pragma unroll
    for (int m = 1; m < 16; m <<= 1)
        #pragma unroll
        for (int rf = 0; rf < 2; ++rf)
            #pragma unroll
            for (int rr = 0; rr < 4; ++rr)
                ssum[rf][rr] += __shfl_xor(ssum[rf][rr], m);

    float* fsm  = (float*)(smem + 131072);
    float* scr  = fsm;          // [4 wc][64 rows]
    float* scm  = fsm + 256;    // [64] masked row scores
    float* wrow = fsm + 320;    // [64] row weights
    float* redv = fsm + 384;    // [2]  m_c, l_c

    if ((lane & 15) == 0) {
        #pragma unroll
        for (int rf = 0; rf < 2; ++rf)
            #pragma unroll
            for (int rr = 0; rr < 4; ++rr)
                scr[wc*64 + wr*32 + rf*16 + (lane >> 4)*4 + rr] = ssum[rf][rr];
    }
    __syncthreads();

    // ---- epilogue 2 (wave 0): combine wc partials, mask, local max, weights
    if (t < 64) {
        float val = (scr[t] + scr[64 + t]) + (scr[128 + t] + scr[192 + t]);
        float mk = mask[(size_t)m0 + t];
        float x = (mk > 0.0f) ? val : -1e30f;
        scm[t] = x;
        float m1 = x;
        #pragma unroll
        for (int mm = 1; mm < 64; mm <<= 1) m1 = fmaxf(m1, __shfl_xor(m1, mm));
        float wv = __expf(x - m1);
        wrow[t] = wv;
        float s1 = wv;
        #pragma unroll
        for (int mm = 1; mm < 64; mm <<= 1) s1 += __shfl_xor(s1, mm);
        if (t == 0) { redv[0] = m1; redv[1] = s1; }
    }
    __syncthreads();

    // ---- epilogue 3: P[e] = sum_r wrow[r] * A_lds[r][e]  (fp32, from LDS)
    {
        int g = t >> 2, w4 = (t & 3);
        float P = 0.f;
        #pragma unroll 8
        for (int r2 = 0; r2 < 64; ++r2) {
            const float* gp = (const float*)&smem[r2*2048 + ((g ^ (r2 & 7)) << 4)];
            P = fmaf(wrow[r2], gp[w4], P);
        }
        Pp[(size_t)mt*E + t] = P;
    }
    if (t == 0) { Ml[mt] = redv[0]; Ll[mt] = redv[1]; }
}

// ---------------------------------------------------------------------------
// K5 (combine + fused MLP): one block per batch. Prologue combines the 32
// chunk partials (flash-softmax identity) into rep, then 3-layer MLP.
// ---------------------------------------------------------------------------
__global__ __launch_bounds__(256)
void k5_mlp(const float* __restrict__ Pp, const float* __restrict__ Ml,
            const float* __restrict__ Ll,
            const float* __restrict__ W1, const float* __restrict__ b1,
            const float* __restrict__ W2, const float* __restrict__ b2,
            const float* __restrict__ W3, const float* __restrict__ b3,
            float* __restrict__ out)
{
    int b = blockIdx.x;              // 64
    int t = threadIdx.x;             // 256
    __shared__ float xL[HD];
    __shared__ float yL[HD];
    __shared__ float wf[32];

    if (t == 0) {
        float M = -3e38f;
        #pragma unroll
        for (int c = 0; c < 32; ++c) M = fmaxf(M, Ml[b*32 + c]);
        float den = 0.f;
        #pragma unroll
        for (int c = 0; c < 32; ++c) den += __expf(Ml[b*32 + c] - M) * Ll[b*32 + c];
        float inv = 1.0f / den;
        #pragma unroll
        for (int c = 0; c < 32; ++c) wf[c] = __expf(Ml[b*32 + c] - M) * inv;
    }
    __syncthreads();

    #pragma unroll
    for (int oo = 0; oo < 2; ++oo) {
        int e = oo*256 + t;
        float sv = 0.f;
        #pragma unroll 8
        for (int c = 0; c < 32; ++c)
            sv += wf[c] * Pp[(size_t)(b*32 + c)*E + e];
        xL[e] = sv;
    }
    __syncthreads();
    #pragma unroll
    for (int oo = 0; oo < 2; ++oo) {
        int h = oo*256 + t;
        float a0 = b1[h], a1 = 0.f, a2 = 0.f, a3 = 0.f;
        #pragma unroll 4
        for (int e = 0; e < E; e += 4) {
            a0 += xL[e]   * W1[(size_t)e*HD + h];
            a1 += xL[e+1] * W1[(size_t)(e+1)*HD + h];
            a2 += xL[e+2] * W1[(size_t)(e+2)*HD + h];
            a3 += xL[e+3] * W1[(size_t)(e+3)*HD + h];
        }
        yL[h] = fmaxf((a0 + a1) + (a2 + a3), 0.f);
    }
    __syncthreads();
    float l2v[2];
    #pragma unroll
    for (int oo = 0; oo < 2; ++oo) {
        int h = oo*256 + t;
        float a0 = b2[h], a1 = 0.f, a2 = 0.f, a3 = 0.f;
        #pragma unroll 4
        for (int e = 0; e < HD; e += 4) {
            a0 += yL[e]   * W2[(size_t)e*HD + h];
            a1 += yL[e+1] * W2[(size_t)(e+1)*HD + h];
            a2 += yL[e+2] * W2[(size_t)(e+2)*HD + h];
            a3 += yL[e+3] * W2[(size_t)(e+3)*HD + h];
        }
        l2v[oo] = fmaxf((a0 + a1) + (a2 + a3), 0.f);
    }
    __syncthreads();
    xL[t] = l2v[0]; xL[256 + t] = l2v[1];
    __syncthreads();
    if (t < TD) {
        float a0 = b3[t], a1 = 0.f, a2 = 0.f, a3 = 0.f;
        #pragma unroll 4
        for (int e = 0; e < HD; e += 4) {
            a0 += xL[e]   * W3[(size_t)e*TD + t];
            a1 += xL[e+1] * W3[(size_t)(e+1)*TD + t];
            a2 += xL[e+2] * W3[(size_t)(e+2)*TD + t];
            a3 += xL[e+3] * W3[(size_t)(e+3)*TD + t];
        }
        out[(size_t)b*TD + t] = (a0 + a1) + (a2 + a3);
    }
}

extern "C" void kernel_launch(void* const* d_in, const int* in_sizes, int n_in,
                              void* d_out, int out_size, void* d_ws, size_t ws_size,
                              hipStream_t stream)
{
    const float* words = (const float*)d_in[0];
    const float* W_att = (const float*)d_in[1];
    const float* b_att = (const float*)d_in[2];
    const float* v     = (const float*)d_in[3];
    const float* W1    = (const float*)d_in[4];
    const float* b1    = (const float*)d_in[5];
    const float* W2    = (const float*)d_in[6];
    const float* b2    = (const float*)d_in[7];
    const float* W3    = (const float*)d_in[8];
    const float* b3    = (const float*)d_in[9];
    (void)in_sizes; (void)n_in; (void)out_size; (void)ws_size;

    float* ws   = (float*)d_ws;
    float* mask = ws + OFF_MASK;
    float* ctxp = ws + OFF_CTXP;
    float* lenp = ws + OFF_LENP;
    float* cb   = ws + OFF_CB;
    float* Pp   = ws + OFF_PP;
    float* Ml   = ws + OFF_ML;
    float* Ll   = ws + OFF_LL;
    unsigned short* Wpk = (unsigned short*)(ws + OFF_WPK);
    float* out  = (float*)d_out;

    hipLaunchKernelGGL(k0_pack,    dim3(1024),   dim3(256), 0, stream, W_att, Wpk);
    hipLaunchKernelGGL(k1_maskcol, dim3(B*8),    dim3(256), 0, stream, words, mask, ctxp, lenp);
    hipLaunchKernelGGL(k2_cb,      dim3(B*2),    dim3(256), 0, stream, W_att, b_att, ctxp, lenp, cb);
    hipLaunchKernelGGL(k3_scores,  dim3(NCHUNK), dim3(512), 0, stream, words, Wpk, cb, v, mask, Pp, Ml, Ll);
    hipLaunchKernelGGL(k5_mlp,     dim3(B),      dim3(256), 0, stream, Pp, Ml, Ll, W1, b1, W2, b2, W3, b3, out);
}

// Round 11
// 330.154 us; speedup vs baseline: 1.1876x; 1.1876x over previous
//
#include <hip/hip_runtime.h>
#include <hip/hip_bf16.h>
#include <hip/hip_fp16.h>
#include <math.h>

// Problem dims
#define B 64
#define S 2048
#define E 512
#define HD 512
#define TD 128
#define M_TOT (B*S)
#define MTILE 64
#define NCHUNK (M_TOT/MTILE)    // 2048 k3 chunks (32 per batch)

// Workspace layout (in floats)
#define OFF_MASK   0                        // B*S
#define OFF_CTXP   (OFF_MASK + B*S)         // 8*B*E
#define OFF_LENP   (OFF_CTXP + 8*B*E)       // 8*B
#define OFF_CB     (OFF_LENP + 8*B)         // B*HD
#define OFF_PP     (OFF_CB + B*HD)          // NCHUNK*E   P partials
#define OFF_ML     (OFF_PP + NCHUNK*E)      // NCHUNK     local maxima
#define OFF_LL     (OFF_ML + NCHUNK)        // NCHUNK     local exp-sums
#define OFF_WPK    (OFF_LL + NCHUNK)        // 262144 fp16 = 131072 floats

typedef __attribute__((ext_vector_type(8))) short short8;
typedef __attribute__((ext_vector_type(4))) float f32x4;

__device__ inline unsigned int f2hu(float x) {
    __half h = __float2half(x);
    unsigned short u; __builtin_memcpy(&u, &h, 2); return (unsigned int)u;
}
__device__ inline float hu2f(unsigned short u) {
    __half h; __builtin_memcpy(&h, &u, 2); return __half2float(h);
}

// fast tanh: exact saturation, ~1e-6 rel err, no NaN (e in (0,1])
__device__ inline float fast_tanh(float x) {
    float a = fabsf(x);
    float e = __expf(-2.0f * a);
    float r = (1.0f - e) / (1.0f + e);
    return copysignf(r, x);
}

// ---------------------------------------------------------------------------
// k0: pack top half of W_att into MFMA B-fragment layout, fp16.
// 16x16x32 f16 B-frag: lane l holds B[k=(l>>4)*8+j][col=l&15].
// Wpk[kstep][fl(32)][lane(64)][j(8)], fl = h>>4
// ---------------------------------------------------------------------------
__global__ __launch_bounds__(256)
void k0_pack(const float* __restrict__ W_att, unsigned short* __restrict__ Wpk)
{
    int tid = blockIdx.x*256 + threadIdx.x;   // 262144 total
    int e = tid >> 9, h = tid & 511;
    float w = W_att[(size_t)e*HD + h];
    int kstep = e >> 5, kb = (e >> 3) & 3, j = e & 7, f = h >> 4, l15 = h & 15;
    size_t dst = ((((size_t)kstep*32 + f)*64) + kb*16 + l15)*8 + j;
    Wpk[dst] = (unsigned short)f2hu(w);
}

// ---------------------------------------------------------------------------
// K1: mask, column partial sums, lengths
// ---------------------------------------------------------------------------
__global__ __launch_bounds__(256)
void k1_maskcol(const float* __restrict__ words, float* __restrict__ mask,
                float* __restrict__ ctxp, float* __restrict__ lenp)
{
    int bid = blockIdx.x;            // 512 = B * 8
    int b = bid >> 3, ch = bid & 7;
    int t = threadIdx.x;
    int w = t >> 6, l = t & 63;
    __shared__ __align__(16) float colred[4][E];
    __shared__ float lenred[4];
    const float* base = words + (size_t)(b * S + ch * 256) * E;
    float4 c0 = make_float4(0.f,0.f,0.f,0.f), c1 = make_float4(0.f,0.f,0.f,0.f);
    float wlen = 0.0f;
    for (int r = w; r < 256; r += 4) {
        const float* row = base + (size_t)r * E;
        float4 a  = *(const float4*)(row + 4*l);
        float4 bb = *(const float4*)(row + 256 + 4*l);
        float rs = a.x+a.y+a.z+a.w + bb.x+bb.y+bb.z+bb.w;
        #pragma unroll
        for (int m = 1; m < 64; m <<= 1) rs += __shfl_xor(rs, m);
        c0.x += a.x;  c0.y += a.y;  c0.z += a.z;  c0.w += a.w;
        c1.x += bb.x; c1.y += bb.y; c1.z += bb.z; c1.w += bb.w;
        if (l == 0) {
            float mv = (rs != 0.0f) ? 1.0f : 0.0f;
            mask[(size_t)b*S + ch*256 + r] = mv;
            wlen += mv;
        }
    }
    *(float4*)&colred[w][4*l]       = c0;
    *(float4*)&colred[w][256 + 4*l] = c1;
    if (l == 0) lenred[w] = wlen;
    __syncthreads();
    float s1 = colred[0][t]+colred[1][t]+colred[2][t]+colred[3][t];
    float s2 = colred[0][t+256]+colred[1][t+256]+colred[2][t+256]+colred[3][t+256];
    size_t o = ((size_t)ch * B + b) * E;
    ctxp[o + t]       = s1;
    ctxp[o + t + 256] = s2;
    if (t == 0) lenp[ch*B + b] = lenred[0]+lenred[1]+lenred[2]+lenred[3];
}

// ---------------------------------------------------------------------------
// K2: cb[b,h] = b_att[h] + context_b . W_att[E:, h]
// ---------------------------------------------------------------------------
__global__ __launch_bounds__(256)
void k2_cb(const float* __restrict__ W_att, const float* __restrict__ b_att,
           const float* __restrict__ ctxp, const float* __restrict__ lenp,
           float* __restrict__ cb)
{
    int bid = blockIdx.x;            // 128
    int b = bid >> 1, hc = bid & 1;
    int t = threadIdx.x;
    __shared__ float ctxL[E];
    float len = 0.f;
    #pragma unroll
    for (int k = 0; k < 8; ++k) len += lenp[k*B + b];
    float inv = 1.0f / len;
    for (int c = t; c < E; c += 256) {
        float sv = 0.f;
        #pragma unroll
        for (int k = 0; k < 8; ++k) sv += ctxp[((size_t)k*B + b)*E + c];
        ctxL[c] = sv * inv;
    }
    __syncthreads();
    int h = hc*256 + t;
    const float* Wb = W_att + (size_t)E * HD;
    float a0 = b_att[h], a1 = 0.f, a2 = 0.f, a3 = 0.f;
    #pragma unroll 4
    for (int e = 0; e < E; e += 4) {
        a0 += ctxL[e]   * Wb[(size_t)e*HD + h];
        a1 += ctxL[e+1] * Wb[(size_t)(e+1)*HD + h];
        a2 += ctxL[e+2] * Wb[(size_t)(e+2)*HD + h];
        a3 += ctxL[e+3] * Wb[(size_t)(e+3)*HD + h];
    }
    cb[(size_t)b*HD + h] = (a0 + a1) + (a2 + a3);
}

// ---------------------------------------------------------------------------
// K3: fp16 MFMA scores + fused local softmax + P-partials.
// Block tile 64(M) x 512(N), 8 waves (2wr x 4wc), wave 32x128, acc[2][8].
// A: whole tile staged ONCE as fp16 FRAG-PACKED in 64KB LDS (conflict-free:
//    writes at t*16 linear, map derived from linear pos; reads lane*16).
//    One barrier total; main loop is barrier-free.
// B: kstep-level register double-buffer from packed Wpk (L2-resident).
// Epilogue: local softmax + P from the fp16 LDS tile (no HBM re-read).
// LDS ~66KB -> 2 blocks/CU: staging of one block overlaps compute of other.
// ---------------------------------------------------------------------------
__global__ __launch_bounds__(512, 4)
void k3_scores(const float* __restrict__ words,
               const unsigned short* __restrict__ Wpk,
               const float* __restrict__ cb, const float* __restrict__ v,
               const float* __restrict__ mask,
               float* __restrict__ Pp, float* __restrict__ Ml, float* __restrict__ Ll)
{
    // 64 KB fp16 frag-packed A-tile + 1.6 KB epilogue scratch
    __shared__ __align__(16) unsigned char smem[65536 + 1600];
    int mt = blockIdx.x;              // 2048 mtiles of 64 rows
    int m0 = mt * MTILE;
    int b  = m0 >> 11;                // S = 2048
    int t = threadIdx.x;
    int lane = t & 63, wid = t >> 6;
    int wr = wid >> 2, wc = wid & 3;  // 2 row-groups x 4 col-groups

    f32x4 acc[2][8];
    #pragma unroll
    for (int i = 0; i < 2; ++i)
        #pragma unroll
        for (int j = 0; j < 8; ++j) acc[i][j] = (f32x4)0.0f;

    // ---- stage whole A tile, frag-packed fp16. Linear pos o = t*16 + i*8192:
    // kstep = i*2 + (t>>8), F=(t>>6)&3, kb=(t>>4)&3, l15=t&15
    // row = F*16+l15; col = kstep*32 + kb*8 (8 consecutive floats -> 8 halves)
    {
        int srow = ((t >> 6) & 3)*16 + (t & 15);
        const float* aBase = words + (size_t)(m0 + srow)*E + ((t >> 4) & 3)*8 + (t >> 8)*32;
        #pragma unroll
        for (int i = 0; i < 8; ++i) {
            const float* s = aBase + i*64;
            float4 x0 = *(const float4*)s;
            float4 x1 = *(const float4*)(s + 4);
            union { uint4 u; __half2 h[4]; } pk;
            pk.h[0] = __float22half2_rn(make_float2(x0.x, x0.y));
            pk.h[1] = __float22half2_rn(make_float2(x0.z, x0.w));
            pk.h[2] = __float22half2_rn(make_float2(x1.x, x1.y));
            pk.h[3] = __float22half2_rn(make_float2(x1.z, x1.w));
            *(uint4*)&smem[t*16 + i*8192] = pk.u;
        }
    }

    // ---- B fragment base: frag fl = wc*8 + cf  (all 512 cols in-block)
    const unsigned short* bBase = Wpk + (((size_t)(wc*8))*64 + lane)*8;
#define LDB(kst,cf) (*(const short8*)(bBase + ((size_t)(kst)*32 + (cf))*512))

    short8 bA[8], bB[8];
    #pragma unroll
    for (int cf = 0; cf < 8; ++cf) bA[cf] = LDB(0, cf);
    __syncthreads();   // staging complete; tile read-only from here

    // ---- barrier-free main loop: 16 ksteps, fully unrolled
    // A-frag read: kstep*4096 + (wr*2+rf)*1024 + lane*16  (linear, no conflict)
#define KBODY(k, BCUR, BNEXT) do { \
        short8 ah0 = *(const short8*)&smem[(k)*4096 + (wr*2    )*1024 + lane*16]; \
        short8 ah1 = *(const short8*)&smem[(k)*4096 + (wr*2 + 1)*1024 + lane*16]; \
        if ((k) < 15) { \
            _Pragma("unroll") \
            for (int cf = 0; cf < 8; ++cf) BNEXT[cf] = LDB((k)+1, cf); \
        } \
        _Pragma("unroll") \
        for (int cf = 0; cf < 8; ++cf) { \
            acc[0][cf] = __builtin_amdgcn_mfma_f32_16x16x32_f16(ah0, BCUR[cf], acc[0][cf], 0, 0, 0); \
            acc[1][cf] = __builtin_amdgcn_mfma_f32_16x16x32_f16(ah1, BCUR[cf], acc[1][cf], 0, 0, 0); \
        } } while(0)

    KBODY( 0, bA, bB);  KBODY( 1, bB, bA);
    KBODY( 2, bA, bB);  KBODY( 3, bB, bA);
    KBODY( 4, bA, bB);  KBODY( 5, bB, bA);
    KBODY( 6, bA, bB);  KBODY( 7, bB, bA);
    KBODY( 8, bA, bB);  KBODY( 9, bB, bA);
    KBODY(10, bA, bB);  KBODY(11, bB, bA);
    KBODY(12, bA, bB);  KBODY(13, bB, bA);
    KBODY(14, bA, bB);  KBODY(15, bB, bA);
#undef KBODY
#undef LDB

    // ---- epilogue 1: tanh(+cb)*v, reduce over this wave's 128 cols
    float ssum[2][4];
    #pragma unroll
    for (int i = 0; i < 2; ++i)
        #pragma unroll
        for (int rr = 0; rr < 4; ++rr) ssum[i][rr] = 0.f;

    #pragma unroll
    for (int cf = 0; cf < 8; ++cf) {
        int col = wc*128 + cf*16 + (lane & 15);
        float cbv = cb[(size_t)b*HD + col];
        float vv  = v[col];
        #pragma unroll
        for (int rf = 0; rf < 2; ++rf)
            #pragma unroll
            for (int rr = 0; rr < 4; ++rr)
                ssum[rf][rr] += fast_tanh(acc[rf][cf][rr] + cbv) * vv;
    }
    #pragma unroll
    for (int m = 1; m < 16; m <<= 1)
        #pragma unroll
        for (int rf = 0; rf < 2; ++rf)
            #pragma unroll
            for (int rr = 0; rr < 4; ++rr)
                ssum[rf][rr] += __shfl_xor(ssum[rf][rr], m);

    float* fsm  = (float*)(smem + 65536);
    float* scr  = fsm;          // [4 wc][64 rows]
    float* scm  = fsm + 256;    // [64] masked row scores
    float* wrow = fsm + 320;    // [64] row weights
    float* redv = fsm + 384;    // [2]  m_c, l_c

    if ((lane & 15) == 0) {
        #pragma unroll
        for (int rf = 0; rf < 2; ++rf)
            #pragma unroll
            for (int rr = 0; rr < 4; ++rr)
                scr[wc*64 + wr*32 + rf*16 + (lane >> 4)*4 + rr] = ssum[rf][rr];
    }
    __syncthreads();

    // ---- epilogue 2 (wave 0): combine wc partials, mask, local max, weights
    if (t < 64) {
        float val = (scr[t] + scr[64 + t]) + (scr[128 + t] + scr[192 + t]);
        float mk = mask[(size_t)m0 + t];
        float x = (mk > 0.0f) ? val : -1e30f;
        scm[t] = x;
        float m1 = x;
        #pragma unroll
        for (int mm = 1; mm < 64; mm <<= 1) m1 = fmaxf(m1, __shfl_xor(m1, mm));
        float wv = __expf(x - m1);
        wrow[t] = wv;
        float s1 = wv;
        #pragma unroll
        for (int mm = 1; mm < 64; mm <<= 1) s1 += __shfl_xor(s1, mm);
        if (t == 0) { redv[0] = m1; redv[1] = s1; }
    }
    __syncthreads();

    // ---- epilogue 3: P[e] = sum_r wrow[r] * A_fp16[r][e]  (from LDS tile)
    {
        int e  = t;                         // one column per thread
        int ks = e >> 5, kb = (e >> 3) & 3, j = e & 7;
        const unsigned char* pbase = &smem[ks*4096 + kb*256 + j*2];
        float P = 0.f;
        #pragma unroll 16
        for (int r2 = 0; r2 < 64; ++r2) {
            unsigned short u = *(const unsigned short*)(pbase + (r2 >> 4)*1024 + (r2 & 15)*16);
            P = fmaf(wrow[r2], hu2f(u), P);
        }
        Pp[(size_t)mt*E + e] = P;
    }
    if (t == 0) { Ml[mt] = redv[0]; Ll[mt] = redv[1]; }
}

// ---------------------------------------------------------------------------
// K5 (combine + fused MLP): one block per batch. Prologue combines the 32
// chunk partials (flash-softmax identity) into rep, then 3-layer MLP.
// ---------------------------------------------------------------------------
__global__ __launch_bounds__(256)
void k5_mlp(const float* __restrict__ Pp, const float* __restrict__ Ml,
            const float* __restrict__ Ll,
            const float* __restrict__ W1, const float* __restrict__ b1,
            const float* __restrict__ W2, const float* __restrict__ b2,
            const float* __restrict__ W3, const float* __restrict__ b3,
            float* __restrict__ out)
{
    int b = blockIdx.x;              // 64
    int t = threadIdx.x;             // 256
    __shared__ float xL[HD];
    __shared__ float yL[HD];
    __shared__ float wf[32];

    if (t == 0) {
        float M = -3e38f;
        #pragma unroll
        for (int c = 0; c < 32; ++c) M = fmaxf(M, Ml[b*32 + c]);
        float den = 0.f;
        #pragma unroll
        for (int c = 0; c < 32; ++c) den += __expf(Ml[b*32 + c] - M) * Ll[b*32 + c];
        float inv = 1.0f / den;
        #pragma unroll
        for (int c = 0; c < 32; ++c) wf[c] = __expf(Ml[b*32 + c] - M) * inv;
    }
    __syncthreads();

    #pragma unroll
    for (int oo = 0; oo < 2; ++oo) {
        int e = oo*256 + t;
        float sv = 0.f;
        #pragma unroll 8
        for (int c = 0; c < 32; ++c)
            sv += wf[c] * Pp[(size_t)(b*32 + c)*E + e];
        xL[e] = sv;
    }
    __syncthreads();
    #pragma unroll
    for (int oo = 0; oo < 2; ++oo) {
        int h = oo*256 + t;
        float a0 = b1[h], a1 = 0.f, a2 = 0.f, a3 = 0.f;
        #pragma unroll 4
        for (int e = 0; e < E; e += 4) {
            a0 += xL[e]   * W1[(size_t)e*HD + h];
            a1 += xL[e+1] * W1[(size_t)(e+1)*HD + h];
            a2 += xL[e+2] * W1[(size_t)(e+2)*HD + h];
            a3 += xL[e+3] * W1[(size_t)(e+3)*HD + h];
        }
        yL[h] = fmaxf((a0 + a1) + (a2 + a3), 0.f);
    }
    __syncthreads();
    float l2v[2];
    #pragma unroll
    for (int oo = 0; oo < 2; ++oo) {
        int h = oo*256 + t;
        float a0 = b2[h], a1 = 0.f, a2 = 0.f, a3 = 0.f;
        #pragma unroll 4
        for (int e = 0; e < HD; e += 4) {
            a0 += yL[e]   * W2[(size_t)e*HD + h];
            a1 += yL[e+1] * W2[(size_t)(e+1)*HD + h];
            a2 += yL[e+2] * W2[(size_t)(e+2)*HD + h];
            a3 += yL[e+3] * W2[(size_t)(e+3)*HD + h];
        }
        l2v[oo] = fmaxf((a0 + a1) + (a2 + a3), 0.f);
    }
    __syncthreads();
    xL[t] = l2v[0]; xL[256 + t] = l2v[1];
    __syncthreads();
    if (t < TD) {
        float a0 = b3[t], a1 = 0.f, a2 = 0.f, a3 = 0.f;
        #pragma unroll 4
        for (int e = 0; e < HD; e += 4) {
            a0 += xL[e]   * W3[(size_t)e*TD + t];
            a1 += xL[e+1] * W3[(size_t)(e+1)*TD + t];
            a2 += xL[e+2] * W3[(size_t)(e+2)*TD + t];
            a3 += xL[e+3] * W3[(size_t)(e+3)*TD + t];
        }
        out[(size_t)b*TD + t] = (a0 + a1) + (a2 + a3);
    }
}

extern "C" void kernel_launch(void* const* d_in, const int* in_sizes, int n_in,
                              void* d_out, int out_size, void* d_ws, size_t ws_size,
                              hipStream_t stream)
{
    const float* words = (const float*)d_in[0];
    const float* W_att = (const float*)d_in[1];
    const float* b_att = (const float*)d_in[2];
    const float* v     = (const float*)d_in[3];
    const float* W1    = (const float*)d_in[4];
    const float* b1    = (const float*)d_in[5];
    const float* W2    = (const float*)d_in[6];
    const float* b2    = (const float*)d_in[7];
    const float* W3    = (const float*)d_in[8];
    const float* b3    = (const float*)d_in[9];
    (void)in_sizes; (void)n_in; (void)out_size; (void)ws_size;

    float* ws   = (float*)d_ws;
    float* mask = ws + OFF_MASK;
    float* ctxp = ws + OFF_CTXP;
    float* lenp = ws + OFF_LENP;
    float* cb   = ws + OFF_CB;
    float* Pp   = ws + OFF_PP;
    float* Ml   = ws + OFF_ML;
    float* Ll   = ws + OFF_LL;
    unsigned short* Wpk = (unsigned short*)(ws + OFF_WPK);
    float* out  = (float*)d_out;

    hipLaunchKernelGGL(k0_pack,    dim3(1024),   dim3(256), 0, stream, W_att, Wpk);
    hipLaunchKernelGGL(k1_maskcol, dim3(B*8),    dim3(256), 0, stream, words, mask, ctxp, lenp);
    hipLaunchKernelGGL(k2_cb,      dim3(B*2),    dim3(256), 0, stream, W_att, b_att, ctxp, lenp, cb);
    hipLaunchKernelGGL(k3_scores,  dim3(NCHUNK), dim3(512), 0, stream, words, Wpk, cb, v, mask, Pp, Ml, Ll);
    hipLaunchKernelGGL(k5_mlp,     dim3(B),      dim3(256), 0, stream, Pp, Ml, Ll, W1, b1, W2, b2, W3, b3, out);
}

// Round 12
// 323.113 us; speedup vs baseline: 1.2134x; 1.0218x over previous
//
#include <hip/hip_runtime.h>
#include <hip/hip_bf16.h>
#include <hip/hip_fp16.h>
#include <math.h>

// Problem dims
#define B 64
#define S 2048
#define E 512
#define HD 512
#define TD 128
#define M_TOT (B*S)
#define MTILE 64
#define NCHUNK (M_TOT/MTILE)    // 2048 k3 chunks (32 per batch)

// Workspace layout (in floats)
#define OFF_MASK   0                        // B*S
#define OFF_CTXP   (OFF_MASK + B*S)         // 8*B*E
#define OFF_LENP   (OFF_CTXP + 8*B*E)       // 8*B
#define OFF_CB     (OFF_LENP + 8*B)         // B*HD
#define OFF_PP     (OFF_CB + B*HD)          // NCHUNK*E   P partials
#define OFF_ML     (OFF_PP + NCHUNK*E)      // NCHUNK     local maxima
#define OFF_LL     (OFF_ML + NCHUNK)        // NCHUNK     local exp-sums
#define OFF_WPK    (OFF_LL + NCHUNK)        // 262144 fp16 = 131072 floats

typedef __attribute__((ext_vector_type(8))) short short8;
typedef __attribute__((ext_vector_type(4))) float f32x4;

__device__ inline unsigned int f2hu(float x) {
    __half h = __float2half(x);
    unsigned short u; __builtin_memcpy(&u, &h, 2); return (unsigned int)u;
}
__device__ inline float hu2f(unsigned short u) {
    __half h; __builtin_memcpy(&h, &u, 2); return __half2float(h);
}

// fast tanh: exact saturation, ~1e-6 rel err, no NaN (e in (0,1])
__device__ inline float fast_tanh(float x) {
    float a = fabsf(x);
    float e = __expf(-2.0f * a);
    float r = (1.0f - e) / (1.0f + e);
    return copysignf(r, x);
}

// ---------------------------------------------------------------------------
// k0: pack top half of W_att into MFMA B-fragment layout, fp16.
// 16x16x32 f16 B-frag: lane l holds B[k=(l>>4)*8+j][col=l&15].
// Wpk[kstep][fl(32)][lane(64)][j(8)], fl = h>>4
// ---------------------------------------------------------------------------
__global__ __launch_bounds__(256)
void k0_pack(const float* __restrict__ W_att, unsigned short* __restrict__ Wpk)
{
    int tid = blockIdx.x*256 + threadIdx.x;   // 262144 total
    int e = tid >> 9, h = tid & 511;
    float w = W_att[(size_t)e*HD + h];
    int kstep = e >> 5, kb = (e >> 3) & 3, j = e & 7, f = h >> 4, l15 = h & 15;
    size_t dst = ((((size_t)kstep*32 + f)*64) + kb*16 + l15)*8 + j;
    Wpk[dst] = (unsigned short)f2hu(w);
}

// ---------------------------------------------------------------------------
// K1: mask, column partial sums, lengths
// ---------------------------------------------------------------------------
__global__ __launch_bounds__(256)
void k1_maskcol(const float* __restrict__ words, float* __restrict__ mask,
                float* __restrict__ ctxp, float* __restrict__ lenp)
{
    int bid = blockIdx.x;            // 512 = B * 8
    int b = bid >> 3, ch = bid & 7;
    int t = threadIdx.x;
    int w = t >> 6, l = t & 63;
    __shared__ __align__(16) float colred[4][E];
    __shared__ float lenred[4];
    const float* base = words + (size_t)(b * S + ch * 256) * E;
    float4 c0 = make_float4(0.f,0.f,0.f,0.f), c1 = make_float4(0.f,0.f,0.f,0.f);
    float wlen = 0.0f;
    for (int r = w; r < 256; r += 4) {
        const float* row = base + (size_t)r * E;
        float4 a  = *(const float4*)(row + 4*l);
        float4 bb = *(const float4*)(row + 256 + 4*l);
        float rs = a.x+a.y+a.z+a.w + bb.x+bb.y+bb.z+bb.w;
        #pragma unroll
        for (int m = 1; m < 64; m <<= 1) rs += __shfl_xor(rs, m);
        c0.x += a.x;  c0.y += a.y;  c0.z += a.z;  c0.w += a.w;
        c1.x += bb.x; c1.y += bb.y; c1.z += bb.z; c1.w += bb.w;
        if (l == 0) {
            float mv = (rs != 0.0f) ? 1.0f : 0.0f;
            mask[(size_t)b*S + ch*256 + r] = mv;
            wlen += mv;
        }
    }
    *(float4*)&colred[w][4*l]       = c0;
    *(float4*)&colred[w][256 + 4*l] = c1;
    if (l == 0) lenred[w] = wlen;
    __syncthreads();
    float s1 = colred[0][t]+colred[1][t]+colred[2][t]+colred[3][t];
    float s2 = colred[0][t+256]+colred[1][t+256]+colred[2][t+256]+colred[3][t+256];
    size_t o = ((size_t)ch * B + b) * E;
    ctxp[o + t]       = s1;
    ctxp[o + t + 256] = s2;
    if (t == 0) lenp[ch*B + b] = lenred[0]+lenred[1]+lenred[2]+lenred[3];
}

// ---------------------------------------------------------------------------
// K2: cb[b,h] = b_att[h] + context_b . W_att[E:, h]
// ---------------------------------------------------------------------------
__global__ __launch_bounds__(256)
void k2_cb(const float* __restrict__ W_att, const float* __restrict__ b_att,
           const float* __restrict__ ctxp, const float* __restrict__ lenp,
           float* __restrict__ cb)
{
    int bid = blockIdx.x;            // 128
    int b = bid >> 1, hc = bid & 1;
    int t = threadIdx.x;
    __shared__ float ctxL[E];
    float len = 0.f;
    #pragma unroll
    for (int k = 0; k < 8; ++k) len += lenp[k*B + b];
    float inv = 1.0f / len;
    for (int c = t; c < E; c += 256) {
        float sv = 0.f;
        #pragma unroll
        for (int k = 0; k < 8; ++k) sv += ctxp[((size_t)k*B + b)*E + c];
        ctxL[c] = sv * inv;
    }
    __syncthreads();
    int h = hc*256 + t;
    const float* Wb = W_att + (size_t)E * HD;
    float a0 = b_att[h], a1 = 0.f, a2 = 0.f, a3 = 0.f;
    #pragma unroll 4
    for (int e = 0; e < E; e += 4) {
        a0 += ctxL[e]   * Wb[(size_t)e*HD + h];
        a1 += ctxL[e+1] * Wb[(size_t)(e+1)*HD + h];
        a2 += ctxL[e+2] * Wb[(size_t)(e+2)*HD + h];
        a3 += ctxL[e+3] * Wb[(size_t)(e+3)*HD + h];
    }
    cb[(size_t)b*HD + h] = (a0 + a1) + (a2 + a3);
}

// ---------------------------------------------------------------------------
// K3: fp16 MFMA scores + fused local softmax + P-partials.
// Block tile 64(M) x 512(N), 8 waves (2wr x 4wc), wave 32x128, acc[2][8].
// A: whole tile staged ONCE as fp16 FRAG-PACKED in 64KB LDS (conflict-free).
//    One barrier; barrier-free main loop (compiler emits COUNTED vmcnt).
// B: DEPTH-2 register pipeline: BCUR[cf] refilled with kstep k+2 right after
//    its last MFMA use (same parity -> same buffer, zero extra registers,
//    ~620cy of L2-latency cover vs ~310cy at depth-1).
// Epilogue: local softmax; P-pass via frag-pattern ds_read_b128 (0-conflict)
//    + 16-lane shfl reduction (replaces the 8-way-conflicted 2B-read pass).
// ---------------------------------------------------------------------------
__global__ __launch_bounds__(512, 4)
void k3_scores(const float* __restrict__ words,
               const unsigned short* __restrict__ Wpk,
               const float* __restrict__ cb, const float* __restrict__ v,
               const float* __restrict__ mask,
               float* __restrict__ Pp, float* __restrict__ Ml, float* __restrict__ Ll)
{
    // 64 KB fp16 frag-packed A-tile + 1.6 KB epilogue scratch
    __shared__ __align__(16) unsigned char smem[65536 + 1600];
    int mt = blockIdx.x;              // 2048 mtiles of 64 rows
    int m0 = mt * MTILE;
    int b  = m0 >> 11;                // S = 2048
    int t = threadIdx.x;
    int lane = t & 63, wid = t >> 6;
    int wr = wid >> 2, wc = wid & 3;  // 2 row-groups x 4 col-groups

    f32x4 acc[2][8];
    #pragma unroll
    for (int i = 0; i < 2; ++i)
        #pragma unroll
        for (int j = 0; j < 8; ++j) acc[i][j] = (f32x4)0.0f;

    // ---- stage whole A tile, frag-packed fp16. Linear pos o = t*16 + i*8192:
    // kstep = i*2 + (t>>8), F=(t>>6)&3, kb=(t>>4)&3, l15=t&15
    // row = F*16+l15; col = kstep*32 + kb*8 (8 consecutive floats -> 8 halves)
    {
        int srow = ((t >> 6) & 3)*16 + (t & 15);
        const float* aBase = words + (size_t)(m0 + srow)*E + ((t >> 4) & 3)*8 + (t >> 8)*32;
        #pragma unroll
        for (int i = 0; i < 8; ++i) {
            const float* s = aBase + i*64;
            float4 x0 = *(const float4*)s;
            float4 x1 = *(const float4*)(s + 4);
            union { uint4 u; __half2 h[4]; } pk;
            pk.h[0] = __float22half2_rn(make_float2(x0.x, x0.y));
            pk.h[1] = __float22half2_rn(make_float2(x0.z, x0.w));
            pk.h[2] = __float22half2_rn(make_float2(x1.x, x1.y));
            pk.h[3] = __float22half2_rn(make_float2(x1.z, x1.w));
            *(uint4*)&smem[t*16 + i*8192] = pk.u;
        }
    }

    // ---- B fragment base: frag fl = wc*8 + cf  (all 512 cols in-block)
    const unsigned short* bBase = Wpk + (((size_t)(wc*8))*64 + lane)*8;
#define LDB(kst,cf) (*(const short8*)(bBase + ((size_t)(kst)*32 + (cf))*512))

    short8 bA[8], bB[8];
    #pragma unroll
    for (int cf = 0; cf < 8; ++cf) bA[cf] = LDB(0, cf);
    #pragma unroll
    for (int cf = 0; cf < 8; ++cf) bB[cf] = LDB(1, cf);
    __syncthreads();   // staging complete; tile read-only from here

    // ---- barrier-free main loop: 16 ksteps, fully unrolled.
    // Depth-2 B pipeline: refill BCUR[cf] with kstep k+2 right after use.
#define KBODY(k, BCUR) do { \
        short8 ah0 = *(const short8*)&smem[(k)*4096 + (wr*2    )*1024 + lane*16]; \
        short8 ah1 = *(const short8*)&smem[(k)*4096 + (wr*2 + 1)*1024 + lane*16]; \
        _Pragma("unroll") \
        for (int cf = 0; cf < 8; ++cf) { \
            acc[0][cf] = __builtin_amdgcn_mfma_f32_16x16x32_f16(ah0, BCUR[cf], acc[0][cf], 0, 0, 0); \
            acc[1][cf] = __builtin_amdgcn_mfma_f32_16x16x32_f16(ah1, BCUR[cf], acc[1][cf], 0, 0, 0); \
            if ((k) < 14) BCUR[cf] = LDB((k)+2, cf); \
        } } while(0)

    KBODY( 0, bA);  KBODY( 1, bB);
    KBODY( 2, bA);  KBODY( 3, bB);
    KBODY( 4, bA);  KBODY( 5, bB);
    KBODY( 6, bA);  KBODY( 7, bB);
    KBODY( 8, bA);  KBODY( 9, bB);
    KBODY(10, bA);  KBODY(11, bB);
    KBODY(12, bA);  KBODY(13, bB);
    KBODY(14, bA);  KBODY(15, bB);
#undef KBODY
#undef LDB

    // ---- epilogue 1: tanh(+cb)*v, reduce over this wave's 128 cols
    float ssum[2][4];
    #pragma unroll
    for (int i = 0; i < 2; ++i)
        #pragma unroll
        for (int rr = 0; rr < 4; ++rr) ssum[i][rr] = 0.f;

    #pragma unroll
    for (int cf = 0; cf < 8; ++cf) {
        int col = wc*128 + cf*16 + (lane & 15);
        float cbv = cb[(size_t)b*HD + col];
        float vv  = v[col];
        #pragma unroll
        for (int rf = 0; rf < 2; ++rf)
            #pragma unroll
            for (int rr = 0; rr < 4; ++rr)
                ssum[rf][rr] += fast_tanh(acc[rf][cf][rr] + cbv) * vv;
    }
    #pragma unroll
    for (int m = 1; m < 16; m <<= 1)
        #pragma unroll
        for (int rf = 0; rf < 2; ++rf)
            #pragma unroll
            for (int rr = 0; rr < 4; ++rr)
                ssum[rf][rr] += __shfl_xor(ssum[rf][rr], m);

    float* fsm  = (float*)(smem + 65536);
    float* scr  = fsm;          // [4 wc][64 rows]
    float* scm  = fsm + 256;    // [64] masked row scores
    float* wrow = fsm + 320;    // [64] row weights
    float* redv = fsm + 384;    // [2]  m_c, l_c

    if ((lane & 15) == 0) {
        #pragma unroll
        for (int rf = 0; rf < 2; ++rf)
            #pragma unroll
            for (int rr = 0; rr < 4; ++rr)
                scr[wc*64 + wr*32 + rf*16 + (lane >> 4)*4 + rr] = ssum[rf][rr];
    }
    __syncthreads();

    // ---- epilogue 2 (wave 0): combine wc partials, mask, local max, weights
    if (t < 64) {
        float val = (scr[t] + scr[64 + t]) + (scr[128 + t] + scr[192 + t]);
        float mk = mask[(size_t)m0 + t];
        float x = (mk > 0.0f) ? val : -1e30f;
        scm[t] = x;
        float m1 = x;
        #pragma unroll
        for (int mm = 1; mm < 64; mm <<= 1) m1 = fmaxf(m1, __shfl_xor(m1, mm));
        float wv = __expf(x - m1);
        wrow[t] = wv;
        float s1 = wv;
        #pragma unroll
        for (int mm = 1; mm < 64; mm <<= 1) s1 += __shfl_xor(s1, mm);
        if (t == 0) { redv[0] = m1; redv[1] = s1; }
    }
    __syncthreads();

    // ---- epilogue 3: P[e] = sum_r wrow[r] * A_fp16[r][e], frag-pattern reads
    // (identical ds_read_b128 pattern as main loop -> 0 bank conflicts).
    // Wave wid handles ksteps {2*wid, 2*wid+1}; lane l holds row l&15 of
    // frag fb, k-elements (l>>4)*8+j. Reduce over the 16-row lane group.
    {
        #pragma unroll
        for (int kk = 0; kk < 2; ++kk) {
            int ks = wid*2 + kk;
            float p8[8];
            #pragma unroll
            for (int j = 0; j < 8; ++j) p8[j] = 0.f;
            #pragma unroll
            for (int fb = 0; fb < 4; ++fb) {
                short8 h = *(const short8*)&smem[ks*4096 + fb*1024 + lane*16];
                float wv = wrow[fb*16 + (lane & 15)];
                #pragma unroll
                for (int j = 0; j < 8; ++j)
                    p8[j] = fmaf(wv, hu2f((unsigned short)h[j]), p8[j]);
            }
            #pragma unroll
            for (int mm = 1; mm < 16; mm <<= 1)
                #pragma unroll
                for (int j = 0; j < 8; ++j)
                    p8[j] += __shfl_xor(p8[j], mm);
            if ((lane & 15) == 0) {
                int c0 = ks*32 + (lane >> 4)*8;
                #pragma unroll
                for (int j = 0; j < 8; ++j)
                    Pp[(size_t)mt*E + c0 + j] = p8[j];
            }
        }
    }
    if (t == 0) { Ml[mt] = redv[0]; Ll[mt] = redv[1]; }
}

// ---------------------------------------------------------------------------
// K5 (combine + fused MLP): one block per batch. Prologue combines the 32
// chunk partials (flash-softmax identity) into rep, then 3-layer MLP.
// ---------------------------------------------------------------------------
__global__ __launch_bounds__(256)
void k5_mlp(const float* __restrict__ Pp, const float* __restrict__ Ml,
            const float* __restrict__ Ll,
            const float* __restrict__ W1, const float* __restrict__ b1,
            const float* __restrict__ W2, const float* __restrict__ b2,
            const float* __restrict__ W3, const float* __restrict__ b3,
            float* __restrict__ out)
{
    int b = blockIdx.x;              // 64
    int t = threadIdx.x;             // 256
    __shared__ float xL[HD];
    __shared__ float yL[HD];
    __shared__ float wf[32];

    if (t == 0) {
        float M = -3e38f;
        #pragma unroll
        for (int c = 0; c < 32; ++c) M = fmaxf(M, Ml[b*32 + c]);
        float den = 0.f;
        #pragma unroll
        for (int c = 0; c < 32; ++c) den += __expf(Ml[b*32 + c] - M) * Ll[b*32 + c];
        float inv = 1.0f / den;
        #pragma unroll
        for (int c = 0; c < 32; ++c) wf[c] = __expf(Ml[b*32 + c] - M) * inv;
    }
    __syncthreads();

    #pragma unroll
    for (int oo = 0; oo < 2; ++oo) {
        int e = oo*256 + t;
        float sv = 0.f;
        #pragma unroll 8
        for (int c = 0; c < 32; ++c)
            sv += wf[c] * Pp[(size_t)(b*32 + c)*E + e];
        xL[e] = sv;
    }
    __syncthreads();
    #pragma unroll
    for (int oo = 0; oo < 2; ++oo) {
        int h = oo*256 + t;
        float a0 = b1[h], a1 = 0.f, a2 = 0.f, a3 = 0.f;
        #pragma unroll 4
        for (int e = 0; e < E; e += 4) {
            a0 += xL[e]   * W1[(size_t)e*HD + h];
            a1 += xL[e+1] * W1[(size_t)(e+1)*HD + h];
            a2 += xL[e+2] * W1[(size_t)(e+2)*HD + h];
            a3 += xL[e+3] * W1[(size_t)(e+3)*HD + h];
        }
        yL[h] = fmaxf((a0 + a1) + (a2 + a3), 0.f);
    }
    __syncthreads();
    float l2v[2];
    #pragma unroll
    for (int oo = 0; oo < 2; ++oo) {
        int h = oo*256 + t;
        float a0 = b2[h], a1 = 0.f, a2 = 0.f, a3 = 0.f;
        #pragma unroll 4
        for (int e = 0; e < HD; e += 4) {
            a0 += yL[e]   * W2[(size_t)e*HD + h];
            a1 += yL[e+1] * W2[(size_t)(e+1)*HD + h];
            a2 += yL[e+2] * W2[(size_t)(e+2)*HD + h];
            a3 += yL[e+3] * W2[(size_t)(e+3)*HD + h];
        }
        l2v[oo] = fmaxf((a0 + a1) + (a2 + a3), 0.f);
    }
    __syncthreads();
    xL[t] = l2v[0]; xL[256 + t] = l2v[1];
    __syncthreads();
    if (t < TD) {
        float a0 = b3[t], a1 = 0.f, a2 = 0.f, a3 = 0.f;
        #pragma unroll 4
        for (int e = 0; e < HD; e += 4) {
            a0 += xL[e]   * W3[(size_t)e*TD + t];
            a1 += xL[e+1] * W3[(size_t)(e+1)*TD + t];
            a2 += xL[e+2] * W3[(size_t)(e+2)*TD + t];
            a3 += xL[e+3] * W3[(size_t)(e+3)*TD + t];
        }
        out[(size_t)b*TD + t] = (a0 + a1) + (a2 + a3);
    }
}

extern "C" void kernel_launch(void* const* d_in, const int* in_sizes, int n_in,
                              void* d_out, int out_size, void* d_ws, size_t ws_size,
                              hipStream_t stream)
{
    const float* words = (const float*)d_in[0];
    const float* W_att = (const float*)d_in[1];
    const float* b_att = (const float*)d_in[2];
    const float* v     = (const float*)d_in[3];
    const float* W1    = (const float*)d_in[4];
    const float* b1    = (const float*)d_in[5];
    const float* W2    = (const float*)d_in[6];
    const float* b2    = (const float*)d_in[7];
    const float* W3    = (const float*)d_in[8];
    const float* b3    = (const float*)d_in[9];
    (void)in_sizes; (void)n_in; (void)out_size; (void)ws_size;

    float* ws   = (float*)d_ws;
    float* mask = ws + OFF_MASK;
    float* ctxp = ws + OFF_CTXP;
    float* lenp = ws + OFF_LENP;
    float* cb   = ws + OFF_CB;
    float* Pp   = ws + OFF_PP;
    float* Ml   = ws + OFF_ML;
    float* Ll   = ws + OFF_LL;
    unsigned short* Wpk = (unsigned short*)(ws + OFF_WPK);
    float* out  = (float*)d_out;

    hipLaunchKernelGGL(k0_pack,    dim3(1024),   dim3(256), 0, stream, W_att, Wpk);
    hipLaunchKernelGGL(k1_maskcol, dim3(B*8),    dim3(256), 0, stream, words, mask, ctxp, lenp);
    hipLaunchKernelGGL(k2_cb,      dim3(B*2),    dim3(256), 0, stream, W_att, b_att, ctxp, lenp, cb);
    hipLaunchKernelGGL(k3_scores,  dim3(NCHUNK), dim3(512), 0, stream, words, Wpk, cb, v, mask, Pp, Ml, Ll);
    hipLaunchKernelGGL(k5_mlp,     dim3(B),      dim3(256), 0, stream, Pp, Ml, Ll, W1, b1, W2, b2, W3, b3, out);
}